// Round 1
// baseline (346.533 us; speedup 1.0000x reference)
//
#include <hip/hip_runtime.h>

// Problem constants (from reference)
#define NQ 6
#define DD 64            // 2^NQ
#define NF 4
#define GG 14
#define KK 3
#define NSIDE 12         // (G-K)/S + 1
#define PP 1728          // NSIDE^3
#define NTRIP 9          // K^3 / 3
#define NC 40
#define BB 16
#define LAM 0.1f
#define FEAT_LEN (NF*PP*NQ)   // 41472

struct cplx { float re, im; };

__device__ inline cplx cmul(cplx a, cplx b) {
    return { a.re*b.re - a.im*b.im, a.re*b.im + a.im*b.re };
}

// PennyLane Rot = RZ(omega) RY(theta) RZ(phi):
// U = [[ep*c, -em*s], [conj(em)*s, conj(ep)*c]]
// ep = exp(-0.5i(phi+omega)), em = exp(0.5i(phi-omega)), c=cos(th/2), s=sin(th/2)
__device__ inline void rotmat(float phi, float th, float om, cplx U[2][2]) {
    float s, c;
    sincosf(0.5f*th, &s, &c);
    float ap = 0.5f*(phi+om), am = 0.5f*(phi-om);
    float sap, cap, sam, cam;
    sincosf(ap, &sap, &cap);
    sincosf(am, &sam, &cam);
    cplx ep = { cap, -sap };   // exp(-i*ap)
    cplx em = { cam,  sam };   // exp(+i*am)
    U[0][0] = {  ep.re*c,  ep.im*c };
    U[0][1] = { -em.re*s, -em.im*s };
    U[1][0] = {  em.re*s, -em.im*s };  // conj(em)*s
    U[1][1] = {  ep.re*c, -ep.im*c };  // conj(ep)*c
}

// Apply 2x2 U on the qubit whose state-index bit mask is `mask`.
// Lane d holds amplitude d; partner differs in `mask` bit.
__device__ inline cplx gate(cplx amp, const cplx U[2][2], int mask, int lane) {
    cplx ap;
    ap.re = __shfl_xor(amp.re, mask);
    ap.im = __shfl_xor(amp.im, mask);
    bool hi = (lane & mask) != 0;
    cplx a0 = hi ? ap  : amp;   // amplitude with bit=0
    cplx a1 = hi ? amp : ap;    // amplitude with bit=1
    cplx uA = hi ? U[1][0] : U[0][0];
    cplx uB = hi ? U[1][1] : U[0][1];
    cplx m0 = cmul(uA, a0), m1 = cmul(uB, a1);
    return { m0.re + m1.re, m0.im + m1.im };
}

// One block per (p,b). 4 waves, wave f simulates feature f.
__global__ __launch_bounds__(256) void sim_kernel(
    const float* __restrict__ x,      // [B,14,14,14]
    const float* __restrict__ theta,  // [NF,1,6,3] flat
    float* __restrict__ feats,        // [B, NF, P, NQ]
    float* __restrict__ ip2)          // [P*B] : sum_{f!=g} ip^2 per (p,b)
{
    int blk = blockIdx.x;             // p*B + b
    int p = blk / BB, b = blk % BB;
    int tid = threadIdx.x;
    int lane = tid & 63;
    int f = tid >> 6;

    __shared__ float sp[27];
    __shared__ float sth[NF*NQ*3];
    __shared__ float sprobs[NF][DD];

    int px = p / (NSIDE*NSIDE), py = (p / NSIDE) % NSIDE, pz = p % NSIDE;
    if (tid < 27) {
        int kx = tid/9, ky = (tid/3)%3, kz = tid%3;
        sp[tid] = x[((size_t)(b*GG + px+kx)*GG + (py+ky))*GG + (pz+kz)];
    }
    if (tid < NF*NQ*3) sth[tid] = theta[tid];
    __syncthreads();

    cplx amp = { (lane==0) ? 1.0f : 0.0f, 0.0f };

    // Encoding: 9 Rot gates, gate k on qubit k%6 (bit mask 1<<(5-(k%6)))
    #pragma unroll
    for (int k = 0; k < NTRIP; ++k) {
        cplx U[2][2];
        rotmat(sp[3*k], sp[3*k+1], sp[3*k+2], U);
        int mask = 1 << (5 - (k % NQ));
        amp = gate(amp, U, mask, lane);
    }

    // CRots for feature f: control i, target (i+1)%6
    #pragma unroll
    for (int i = 0; i < NQ; ++i) {
        cplx U[2][2];
        const float* tt = &sth[(f*NQ + i)*3];
        rotmat(tt[0], tt[1], tt[2], U);
        int cmask = 1 << (5 - i);
        int tmask = 1 << (5 - ((i+1) % NQ));
        cplx na = gate(amp, U, tmask, lane);
        if (lane & cmask) amp = na;   // only control=1 lanes rotated
    }

    float pr = amp.re*amp.re + amp.im*amp.im;
    sprobs[f][lane] = pr;
    __syncthreads();

    // Z-expectation per qubit q: sum_d (1-2*bit(d,5-q)) * prob[d]
    if (lane < NQ) {
        int shift = 5 - lane;
        float e = 0.f;
        #pragma unroll
        for (int d = 0; d < DD; ++d) {
            float q = sprobs[f][d];
            e = ((d >> shift) & 1) ? e - q : e + q;
        }
        feats[(((size_t)b*NF + f)*PP + p)*NQ + lane] = e;
    }

    // Loss contribution: sum over ordered f!=g of (dot(probs_f,probs_g))^2
    if (f == 0) {
        const int pfi[6] = {0,0,0,1,1,2};
        const int pgi[6] = {1,2,3,2,3,3};
        float acc = 0.f;
        #pragma unroll
        for (int k = 0; k < 6; ++k) {
            float v = sprobs[pfi[k]][lane] * sprobs[pgi[k]][lane];
            #pragma unroll
            for (int m = 1; m < 64; m <<= 1) v += __shfl_xor(v, m);
            acc += 2.0f * v * v;    // (f,g) and (g,f)
        }
        if (lane == 0) ip2[blk] = acc;
    }
}

// Deterministic reduction of ip2 -> loss scalar at out[B*NC]
__global__ __launch_bounds__(256) void loss_kernel(
    const float* __restrict__ ip2, float* __restrict__ out)
{
    __shared__ float red[256];
    float acc = 0.f;
    for (int i = threadIdx.x; i < PP*BB; i += 256) acc += ip2[i];
    red[threadIdx.x] = acc;
    __syncthreads();
    for (int s = 128; s > 0; s >>= 1) {
        if (threadIdx.x < s) red[threadIdx.x] += red[threadIdx.x + s];
        __syncthreads();
    }
    if (threadIdx.x == 0)
        out[BB*NC] = red[0] * (LAM / (float)(NF*(NF-1)) / (float)BB);
}

// logits[b,c] = bias[c] + dot(feats[b,:], W[c,:]) over FEAT_LEN
__global__ __launch_bounds__(256) void logits_kernel(
    const float* __restrict__ feats, const float* __restrict__ W,
    const float* __restrict__ bias, float* __restrict__ out)
{
    int bc = blockIdx.x;              // b*NC + c
    int b = bc / NC, c = bc % NC;
    const float* fv = feats + (size_t)b * FEAT_LEN;
    const float* wv = W + (size_t)c * FEAT_LEN;
    float acc = 0.f;
    for (int j = threadIdx.x; j < FEAT_LEN; j += 256) acc += fv[j] * wv[j];
    #pragma unroll
    for (int m = 1; m < 64; m <<= 1) acc += __shfl_xor(acc, m);
    __shared__ float red[4];
    int lane = threadIdx.x & 63, w = threadIdx.x >> 6;
    if (lane == 0) red[w] = acc;
    __syncthreads();
    if (threadIdx.x == 0)
        out[bc] = red[0] + red[1] + red[2] + red[3] + bias[c];
}

extern "C" void kernel_launch(void* const* d_in, const int* in_sizes, int n_in,
                              void* d_out, int out_size, void* d_ws, size_t ws_size,
                              hipStream_t stream) {
    const float* x     = (const float*)d_in[0];  // [16,14,14,14]
    const float* theta = (const float*)d_in[1];  // [4,1,6,3]
    const float* W     = (const float*)d_in[2];  // [40,41472]
    const float* bias  = (const float*)d_in[3];  // [40]
    float* out = (float*)d_out;                  // [640 logits][1 loss]

    float* feats = (float*)d_ws;                        // B*FEAT_LEN floats
    float* ip2   = feats + (size_t)BB * FEAT_LEN;       // P*B floats

    sim_kernel<<<PP*BB, 256, 0, stream>>>(x, theta, feats, ip2);
    loss_kernel<<<1, 256, 0, stream>>>(ip2, out);
    logits_kernel<<<BB*NC, 256, 0, stream>>>(feats, W, bias, out);
}

// Round 2
// 154.211 us; speedup vs baseline: 2.2471x; 2.2471x over previous
//
#include <hip/hip_runtime.h>

// Problem constants (from reference)
#define NQ 6
#define DD 64            // 2^NQ
#define NF 4
#define GG 14
#define KK 3
#define NSIDE 12         // (G-K)/S + 1
#define PP 1728          // NSIDE^3
#define NTRIP 9          // K^3 / 3
#define NC 40
#define BB 16
#define LAM 0.1f
#define FEAT_LEN (NF*PP*NQ)   // 41472

struct cplx { float re, im; };

// PennyLane Rot = RZ(omega) RY(theta) RZ(phi):
// U = [[ep*c, -em*s], [conj(em)*s, conj(ep)*c]]
// ep = exp(-0.5i(phi+omega)), em = exp(0.5i(phi-omega)), c=cos(th/2), s=sin(th/2)
__device__ inline void rotmat(float phi, float th, float om, cplx U[2][2]) {
    float s, c;
    sincosf(0.5f*th, &s, &c);
    float ap = 0.5f*(phi+om), am = 0.5f*(phi-om);
    float sap, cap, sam, cam;
    sincosf(ap, &sap, &cap);
    sincosf(am, &sam, &cam);
    U[0][0] = {  cap*c, -sap*c };
    U[0][1] = { -cam*s, -sam*s };
    U[1][0] = {  cam*s, -sam*s };
    U[1][1] = {  cap*c,  sap*c };
}

// Precompute the 24 CRot 2x2 matrices (block-invariant).
__global__ __launch_bounds__(64) void crot_init(
    const float* __restrict__ theta, float* __restrict__ crotU)
{
    int t = threadIdx.x;
    if (t >= NF*NQ) return;
    const float* a = theta + t*3;
    cplx U[2][2];
    rotmat(a[0], a[1], a[2], U);
    float* o = crotU + t*8;
    o[0]=U[0][0].re; o[1]=U[0][0].im; o[2]=U[0][1].re; o[3]=U[0][1].im;
    o[4]=U[1][0].re; o[5]=U[1][0].im; o[6]=U[1][1].re; o[7]=U[1][1].im;
}

// Apply mix: new = uA*a0 + uB*a1 where a0/a1 chosen by hi bit.
__device__ inline cplx mix(cplx amp, cplx uA, cplx uB, int mask, int lane) {
    cplx ap;
    ap.re = __shfl_xor(amp.re, mask);
    ap.im = __shfl_xor(amp.im, mask);
    bool hi = (lane & mask) != 0;
    cplx a0 = hi ? ap  : amp;
    cplx a1 = hi ? amp : ap;
    cplx r;
    r.re = uA.re*a0.re - uA.im*a0.im + uB.re*a1.re - uB.im*a1.im;
    r.im = uA.re*a0.im + uA.im*a0.re + uB.re*a1.im + uB.im*a1.re;
    return r;
}

// One block per (p,b). 4 waves, wave f simulates feature f.
__global__ __launch_bounds__(256) void sim_kernel(
    const float* __restrict__ x,      // [B,14,14,14]
    const float* __restrict__ crotU,  // [NF*NQ][8]
    float* __restrict__ feats,        // [B, NF, P, NQ]
    float* __restrict__ ip2)          // [P*B] : sum_{f!=g} ip^2 per (p,b)
{
    int blk = blockIdx.x;             // p*B + b
    int p = blk / BB, b = blk % BB;
    int tid = threadIdx.x;
    int lane = tid & 63;
    int f = tid >> 6;

    __shared__ float sp[27];
    __shared__ float ssin[27], scos[27];
    __shared__ float4 scrot[NF*NQ*2];
    __shared__ float sprobs[NF][DD];

    int px = p / (NSIDE*NSIDE), py = (p / NSIDE) % NSIDE, pz = p % NSIDE;
    if (tid < 27) {
        int kx = tid/9, ky = (tid/3)%3, kz = tid%3;
        sp[tid] = x[((size_t)(b*GG + px+kx)*GG + (py+ky))*GG + (pz+kz)];
    }
    if (tid < NF*NQ*2) scrot[tid] = ((const float4*)crotU)[tid];
    __syncthreads();

    // 27 distinct trig args for the 9 encoding gates:
    // idx 3k+0: 0.5*theta, 3k+1: 0.5*(phi+omega), 3k+2: 0.5*(phi-omega)
    if (tid < 27) {
        int k = tid / 3, r = tid % 3;
        float phi = sp[3*k], th = sp[3*k+1], om = sp[3*k+2];
        float arg = (r == 0) ? 0.5f*th : (r == 1) ? 0.5f*(phi+om) : 0.5f*(phi-om);
        float s, c;
        sincosf(arg, &s, &c);
        ssin[tid] = s; scos[tid] = c;
    }
    __syncthreads();

    cplx amp = { (lane==0) ? 1.0f : 0.0f, 0.0f };

    // Encoding: 9 Rot gates, gate k on qubit k%6 (bit mask 1<<(5-(k%6)))
    #pragma unroll
    for (int k = 0; k < NTRIP; ++k) {
        float s   = ssin[3*k],   c   = scos[3*k];
        float sap = ssin[3*k+1], cap = scos[3*k+1];
        float sam = ssin[3*k+2], cam = scos[3*k+2];
        float t1 = cap*c, t2 = sap*c, t3 = cam*s, t4 = sam*s;
        int mask = 1 << (5 - (k % NQ));
        bool hi = (lane & mask) != 0;
        // uA = hi?U10:U00, uB = hi?U11:U01
        cplx uA = { hi ?  t3 :  t1, hi ? -t4 : -t2 };
        cplx uB = { hi ?  t1 : -t3, hi ?  t2 : -t4 };
        amp = mix(amp, uA, uB, mask, lane);
    }

    // CRots for feature f: control i, target (i+1)%6 (precomputed U)
    #pragma unroll
    for (int i = 0; i < NQ; ++i) {
        float4 A = scrot[(f*NQ + i)*2];
        float4 Bq = scrot[(f*NQ + i)*2 + 1];
        int cmask = 1 << (5 - i);
        int tmask = 1 << (5 - ((i+1) % NQ));
        bool hi = (lane & tmask) != 0;
        cplx uA = { hi ? Bq.x : A.x, hi ? Bq.y : A.y };
        cplx uB = { hi ? Bq.z : A.z, hi ? Bq.w : A.w };
        cplx na = mix(amp, uA, uB, tmask, lane);
        if (lane & cmask) amp = na;   // only control=1 lanes rotated
    }

    float pr = amp.re*amp.re + amp.im*amp.im;
    sprobs[f][lane] = pr;

    // All 6 Z-expectations via one Walsh-Hadamard butterfly:
    // after 6 stages lane l holds sum_d (-1)^popc(l&d) pr_d;
    // single-bit lanes l=1<<shift carry expval of qubit q=5-shift.
    float v = pr;
    #pragma unroll
    for (int m = 1; m < 64; m <<= 1) {
        float o = __shfl_xor(v, m);
        v = (lane & m) ? (o - v) : (v + o);
    }
    if (lane && !(lane & (lane - 1))) {
        int shift = __ffs(lane) - 1;
        int q = 5 - shift;
        feats[(((size_t)b*NF + f)*PP + p)*NQ + q] = v;
    }
    __syncthreads();

    // Loss contribution: sum over ordered f!=g of (dot(probs_f,probs_g))^2
    if (f == 0) {
        const int pfi[6] = {0,0,0,1,1,2};
        const int pgi[6] = {1,2,3,2,3,3};
        float acc = 0.f;
        #pragma unroll
        for (int k = 0; k < 6; ++k) {
            float w = sprobs[pfi[k]][lane] * sprobs[pgi[k]][lane];
            #pragma unroll
            for (int m = 1; m < 64; m <<= 1) w += __shfl_xor(w, m);
            acc += 2.0f * w * w;    // (f,g) and (g,f)
        }
        if (lane == 0) ip2[blk] = acc;
    }
}

// Deterministic reduction of ip2 -> loss scalar at out[B*NC]
__global__ __launch_bounds__(256) void loss_kernel(
    const float* __restrict__ ip2, float* __restrict__ out)
{
    __shared__ float red[256];
    float acc = 0.f;
    for (int i = threadIdx.x; i < PP*BB; i += 256) acc += ip2[i];
    red[threadIdx.x] = acc;
    __syncthreads();
    for (int s = 128; s > 0; s >>= 1) {
        if (threadIdx.x < s) red[threadIdx.x] += red[threadIdx.x + s];
        __syncthreads();
    }
    if (threadIdx.x == 0)
        out[BB*NC] = red[0] * (LAM / (float)(NF*(NF-1)) / (float)BB);
}

// logits[b,c] = bias[c] + dot(feats[b,:], W[c,:]) over FEAT_LEN
__global__ __launch_bounds__(256) void logits_kernel(
    const float* __restrict__ feats, const float* __restrict__ W,
    const float* __restrict__ bias, float* __restrict__ out)
{
    int bc = blockIdx.x;              // b*NC + c
    int b = bc / NC, c = bc % NC;
    const float* fv = feats + (size_t)b * FEAT_LEN;
    const float* wv = W + (size_t)c * FEAT_LEN;
    float acc = 0.f;
    for (int j = threadIdx.x; j < FEAT_LEN; j += 256) acc += fv[j] * wv[j];
    #pragma unroll
    for (int m = 1; m < 64; m <<= 1) acc += __shfl_xor(acc, m);
    __shared__ float red[4];
    int lane = threadIdx.x & 63, w = threadIdx.x >> 6;
    if (lane == 0) red[w] = acc;
    __syncthreads();
    if (threadIdx.x == 0)
        out[bc] = red[0] + red[1] + red[2] + red[3] + bias[c];
}

extern "C" void kernel_launch(void* const* d_in, const int* in_sizes, int n_in,
                              void* d_out, int out_size, void* d_ws, size_t ws_size,
                              hipStream_t stream) {
    const float* x     = (const float*)d_in[0];  // [16,14,14,14]
    const float* theta = (const float*)d_in[1];  // [4,1,6,3]
    const float* W     = (const float*)d_in[2];  // [40,41472]
    const float* bias  = (const float*)d_in[3];  // [40]
    float* out = (float*)d_out;                  // [640 logits][1 loss]

    float* feats = (float*)d_ws;                        // B*FEAT_LEN floats
    float* ip2   = feats + (size_t)BB * FEAT_LEN;       // P*B floats
    float* crotU = ip2 + (size_t)PP * BB;               // 192 floats

    crot_init<<<1, 64, 0, stream>>>(theta, crotU);
    sim_kernel<<<PP*BB, 256, 0, stream>>>(x, crotU, feats, ip2);
    loss_kernel<<<1, 256, 0, stream>>>(ip2, out);
    logits_kernel<<<BB*NC, 256, 0, stream>>>(feats, W, bias, out);
}

// Round 3
// 129.305 us; speedup vs baseline: 2.6800x; 1.1926x over previous
//
#include <hip/hip_runtime.h>

// Problem constants (from reference)
#define NQ 6
#define DD 64            // 2^NQ
#define NF 4
#define GG 14
#define GG2 196
#define GG3 2744
#define NSIDE 12
#define PP 1728          // NSIDE^3
#define NC 40
#define BB 16
#define LAM 0.1f
#define FEAT_LEN (NF*PP*NQ)   // 41472
#define KCH 512
#define NCHUNK 81             // 41472 / 512
#define CTILES 5              // 40 / 8

// ---------- small helpers ----------

template<int CTRL>
__device__ __forceinline__ float fdpp(float v) {
    return __int_as_float(__builtin_amdgcn_mov_dpp(__float_as_int(v), CTRL, 0xF, 0xF, true));
}
// quad_perm ctrl codes: xor1=[1,0,3,2]=0xB1, xor2=[2,3,0,1]=0x4E, xor3=[3,2,1,0]=0x1B

// Apply 2x2 gate U on state-index bit MASK (1-qubit gate), all 32 pairs.
template<int MASK>
__device__ __forceinline__ void gate1(float* ar, float* ai,
    float u00r, float u00i, float u01r, float u01i,
    float u10r, float u10i, float u11r, float u11i)
{
    #pragma unroll
    for (int d0 = 0; d0 < DD; ++d0) {
        if (d0 & MASK) continue;
        const int d1 = d0 | MASK;
        float a0r = ar[d0], a0i = ai[d0];
        float a1r = ar[d1], a1i = ai[d1];
        ar[d0] = u00r*a0r - u00i*a0i + u01r*a1r - u01i*a1i;
        ai[d0] = u00r*a0i + u00i*a0r + u01r*a1i + u01i*a1r;
        ar[d1] = u10r*a0r - u10i*a0i + u11r*a1r - u11i*a1i;
        ai[d1] = u10r*a0i + u10i*a0r + u11r*a1i + u11i*a1r;
    }
}

// Controlled Rot: apply U on target bit TMASK only where control bit CMASK=1.
template<int CMASK, int TMASK>
__device__ __forceinline__ void crot(float* ar, float* ai,
    float u00r, float u00i, float u01r, float u01i,
    float u10r, float u10i, float u11r, float u11i)
{
    #pragma unroll
    for (int d0 = 0; d0 < DD; ++d0) {
        if (!(d0 & CMASK) || (d0 & TMASK)) continue;
        const int d1 = d0 | TMASK;
        float a0r = ar[d0], a0i = ai[d0];
        float a1r = ar[d1], a1i = ai[d1];
        ar[d0] = u00r*a0r - u00i*a0i + u01r*a1r - u01i*a1i;
        ai[d0] = u00r*a0i + u00i*a0r + u01r*a1i + u01i*a1r;
        ar[d1] = u10r*a0r - u10i*a0i + u11r*a1r - u11i*a1i;
        ai[d1] = u10r*a0i + u10i*a0r + u11r*a1i + u11i*a1r;
    }
}

// ---------- sim: one thread = one circuit (p,b,f); block = one p ----------

__global__ __launch_bounds__(64, 2) void sim_kernel(
    const float* __restrict__ x,      // [B,14,14,14]
    const float* __restrict__ theta,  // [NF,1,6,3]
    float* __restrict__ feats,        // [B][NF][PP][NQ]
    float* __restrict__ ip2)          // [PP]
{
    const int p = blockIdx.x;
    const int t = threadIdx.x;        // 64 threads = 1 wave
    const int b = t >> 2, f = t & 3;

    __shared__ __align__(16) float scrot[NF*NQ][8];
    if (t < NF*NQ) {
        const float* a = theta + t*3;
        float s, c, sap, cap, sam, cam;
        __sincosf(0.5f*a[1], &s, &c);
        __sincosf(0.5f*(a[0]+a[2]), &sap, &cap);
        __sincosf(0.5f*(a[0]-a[2]), &sam, &cam);
        scrot[t][0] =  cap*c; scrot[t][1] = -sap*c;
        scrot[t][2] = -cam*s; scrot[t][3] = -sam*s;
        scrot[t][4] =  cam*s; scrot[t][5] = -sam*s;
        scrot[t][6] =  cap*c; scrot[t][7] =  sap*c;
    }

    // patch values (27 loads, compile-time offsets from one base)
    const int px = p/(NSIDE*NSIDE), py = (p/NSIDE)%NSIDE, pz = p%NSIDE;
    const float* xp = x + (size_t)b*GG3 + px*GG2 + py*GG + pz;
    float spv[27];
    #pragma unroll
    for (int i = 0; i < 27; ++i) {
        const int kx = i/9, ky = (i/3)%3, kz = i%3;
        spv[i] = xp[kx*GG2 + ky*GG + kz];
    }
    __syncthreads();

    float ar[DD], ai[DD];
    #pragma unroll
    for (int d = 0; d < DD; ++d) { ar[d] = 0.f; ai[d] = 0.f; }
    ar[0] = 1.f;

    // encoding gates: gate k on qubit k%6 -> mask 1<<(5-(k%6))
    #define ENC(K, MASK) { \
        float s_, c_, sap_, cap_, sam_, cam_; \
        __sincosf(0.5f*spv[3*(K)+1], &s_, &c_); \
        __sincosf(0.5f*(spv[3*(K)]+spv[3*(K)+2]), &sap_, &cap_); \
        __sincosf(0.5f*(spv[3*(K)]-spv[3*(K)+2]), &sam_, &cam_); \
        float t1 = cap_*c_, t2 = sap_*c_, t3 = cam_*s_, t4 = sam_*s_; \
        gate1<MASK>(ar, ai, t1, -t2, -t3, -t4, t3, -t4, t1, t2); }

    ENC(0, 32) ENC(1, 16) ENC(2, 8) ENC(3, 4) ENC(4, 2) ENC(5, 1)
    ENC(6, 32) ENC(7, 16) ENC(8, 8)
    #undef ENC

    // CRot layer for feature f: control i -> target (i+1)%6
    #define CR(I, CM, TM) { \
        float4 A  = *(const float4*)&scrot[f*NQ + (I)][0]; \
        float4 Bq = *(const float4*)&scrot[f*NQ + (I)][4]; \
        crot<CM, TM>(ar, ai, A.x, A.y, A.z, A.w, Bq.x, Bq.y, Bq.z, Bq.w); }

    CR(0, 32, 16) CR(1, 16, 8) CR(2, 8, 4) CR(3, 4, 2) CR(4, 2, 1) CR(5, 1, 32)
    #undef CR

    // probabilities
    float pr[DD];
    #pragma unroll
    for (int d = 0; d < DD; ++d) pr[d] = ar[d]*ar[d] + ai[d]*ai[d];

    // loss pair-dots via DPP quad_perm (threads of a quad share (p,b), differ in f)
    float dot1 = 0.f, dot2 = 0.f, dot3 = 0.f;
    #pragma unroll
    for (int d = 0; d < DD; ++d) {
        dot1 += pr[d] * fdpp<0xB1>(pr[d]);
        dot2 += pr[d] * fdpp<0x4E>(pr[d]);
        dot3 += pr[d] * fdpp<0x1B>(pr[d]);
    }
    float lc = dot1*dot1 + dot2*dot2 + dot3*dot3;
    #pragma unroll
    for (int m = 1; m < 64; m <<= 1) lc += __shfl_xor(lc, m);
    if (t == 0) ip2[p] = lc;

    // expvals: signed reduction tree over pr (in place).
    // level lvl handles bit mask 1<<lvl -> qubit q = 5-lvl
    float ev[NQ];
    #pragma unroll
    for (int lvl = 0; lvl < NQ; ++lvl) {
        const int n = DD >> (lvl + 1);
        float diff = 0.f;
        #pragma unroll
        for (int i = 0; i < n; ++i) diff += pr[2*i] - pr[2*i+1];
        ev[5 - lvl] = diff;
        #pragma unroll
        for (int i = 0; i < n; ++i) pr[i] = pr[2*i] + pr[2*i+1];
    }

    float* fo = feats + (((size_t)b*NF + f)*PP + p)*NQ;
    #pragma unroll
    for (int q = 0; q < NQ; ++q) fo[q] = ev[q];
}

// ---------- logits phase A: K-split, W read once ----------

__global__ __launch_bounds__(128) void logitsA(
    const float* __restrict__ feats,   // [BB][FEAT_LEN]
    const float* __restrict__ W,       // [NC][FEAT_LEN]
    float* __restrict__ partial)       // [NC][BB][NCHUNK]
{
    const int chunk = blockIdx.x;      // 0..80
    const int ctile = blockIdx.y;      // 0..4
    const int t = threadIdx.x;         // 128
    const int jbase = chunk * KCH;

    __shared__ __align__(16) float fs[BB][KCH + 4];   // +4 pad: kill bank conflicts

    #pragma unroll
    for (int i = 0; i < 16; ++i) {
        const int gi = i*128 + t;      // 0..2047 float4s
        const int br = gi >> 7;        // feats row
        const int c4 = gi & 127;       // float4 within row
        float4 v = *(const float4*)(feats + (size_t)br*FEAT_LEN + jbase + c4*4);
        *(float4*)&fs[br][c4*4] = v;
    }
    __syncthreads();

    const int cl = t >> 4, b = t & 15;
    const int c = ctile*8 + cl;
    const float* wr = W + (size_t)c*FEAT_LEN + jbase;
    float acc = 0.f;
    #pragma unroll 8
    for (int j4 = 0; j4 < KCH/4; ++j4) {
        float4 wv = *(const float4*)(wr + j4*4);
        float4 fv = *(const float4*)&fs[b][j4*4];
        acc += wv.x*fv.x + wv.y*fv.y + wv.z*fv.z + wv.w*fv.w;
    }
    partial[((size_t)c*BB + b)*NCHUNK + chunk] = acc;
}

// ---------- phase B: logits reduce + bias, and loss reduce ----------

__global__ __launch_bounds__(768) void finalize_kernel(
    const float* __restrict__ partial, const float* __restrict__ bias,
    const float* __restrict__ ip2, float* __restrict__ out)
{
    const int t = threadIdx.x;
    if (t < BB*NC) {
        const int b = t / NC, c = t % NC;
        const float* pp = partial + ((size_t)c*BB + b)*NCHUNK;
        float acc = bias[c];
        #pragma unroll 27
        for (int i = 0; i < NCHUNK; ++i) acc += pp[i];
        out[t] = acc;                  // out[b*NC + c]
    } else if (t >= 704) {
        const int lane = t - 704;      // wave 11, all 64 lanes
        float acc = 0.f;
        for (int i = lane; i < PP; i += 64) acc += ip2[i];
        #pragma unroll
        for (int m = 1; m < 64; m <<= 1) acc += __shfl_xor(acc, m);
        if (lane == 0)
            out[BB*NC] = acc * (LAM / (float)(NF*(NF-1)) / (float)BB);
    }
}

extern "C" void kernel_launch(void* const* d_in, const int* in_sizes, int n_in,
                              void* d_out, int out_size, void* d_ws, size_t ws_size,
                              hipStream_t stream) {
    const float* x     = (const float*)d_in[0];  // [16,14,14,14]
    const float* theta = (const float*)d_in[1];  // [4,1,6,3]
    const float* W     = (const float*)d_in[2];  // [40,41472]
    const float* bias  = (const float*)d_in[3];  // [40]
    float* out = (float*)d_out;                  // [640 logits][1 loss]

    float* feats   = (float*)d_ws;                       // BB*FEAT_LEN
    float* ip2     = feats + (size_t)BB * FEAT_LEN;      // PP
    float* partial = ip2 + PP;                           // NC*BB*NCHUNK

    sim_kernel<<<PP, 64, 0, stream>>>(x, theta, feats, ip2);
    logitsA<<<dim3(NCHUNK, CTILES), 128, 0, stream>>>(feats, W, partial);
    finalize_kernel<<<1, 768, 0, stream>>>(partial, bias, ip2, out);
}

// Round 4
// 44.361 us; speedup vs baseline: 7.8117x; 2.9148x over previous
//
#include <hip/hip_runtime.h>

// Problem constants (from reference)
#define NQ 6
#define DD 64            // 2^NQ
#define NF 4
#define GG 14
#define GG2 196
#define GG3 2744
#define NSIDE 12
#define PP 1728          // NSIDE^3
#define NC 40
#define BB 16
#define LAM 0.1f
#define FEAT_LEN (NF*PP*NQ)   // 41472
#define KCH 512
#define NCHUNK 81             // 41472 / 512
#define CTILES 5              // 40 / 8
#define PBLK 4                // patches per block

// ---------- small helpers ----------

template<int CTRL>
__device__ __forceinline__ float fdpp(float v) {
    return __int_as_float(__builtin_amdgcn_mov_dpp(__float_as_int(v), CTRL, 0xF, 0xF, true));
}
// quad_perm ctrl: xor1=0xB1, xor2=0x4E, xor3=0x1B

// First column (u00,u10) of PennyLane Rot(phi,th,om)
__device__ __forceinline__ void rotcol(float phi, float th, float om,
    float& c0r, float& c0i, float& c1r, float& c1i)
{
    float s, c, sap, cap, sam, cam;
    __sincosf(0.5f*th, &s, &c);
    __sincosf(0.5f*(phi+om), &sap, &cap);
    __sincosf(0.5f*(phi-om), &sam, &cam);
    c0r = cap*c; c0i = -sap*c;
    c1r = cam*s; c1i = -sam*s;
}

// 1q gate on bit MASK where all bit=1 amplitudes are zero (support = multiples
// of 2*MASK). Only the first column of U is needed: 8 ops/pair.
template<int MASK>
__device__ __forceinline__ void spread(float* ar, float* ai,
    float c0r, float c0i, float c1r, float c1i)
{
    #pragma unroll
    for (int i = 0; i < 32/MASK; ++i) {
        const int d0 = i*2*MASK, d1 = d0 + MASK;
        float a0r = ar[d0], a0i = ai[d0];
        ar[d1] = c1r*a0r - c1i*a0i;
        ai[d1] = c1r*a0i + c1i*a0r;
        ar[d0] = c0r*a0r - c0i*a0i;
        ai[d0] = c0r*a0i + c0i*a0r;
    }
}

// Controlled Rot: apply U on target bit TMASK only where control bit CMASK=1.
template<int CMASK, int TMASK>
__device__ __forceinline__ void crot(float* ar, float* ai,
    float u00r, float u00i, float u01r, float u01i,
    float u10r, float u10i, float u11r, float u11i)
{
    #pragma unroll
    for (int d0 = 0; d0 < DD; ++d0) {
        if (!(d0 & CMASK) || (d0 & TMASK)) continue;
        const int d1 = d0 | TMASK;
        float a0r = ar[d0], a0i = ai[d0];
        float a1r = ar[d1], a1i = ai[d1];
        ar[d0] = u00r*a0r - u00i*a0i + u01r*a1r - u01i*a1i;
        ai[d0] = u00r*a0i + u00i*a0r + u01r*a1i + u01i*a1r;
        ar[d1] = u10r*a0r - u10i*a0i + u11r*a1r - u11i*a1i;
        ai[d1] = u10r*a0i + u10i*a0r + u11r*a1i + u11i*a1r;
    }
}

// ---------- sim: one thread = one circuit (p,b,f); block = 4 p's ----------

__global__ __launch_bounds__(256, 1) void sim_kernel(
    const float* __restrict__ x,      // [B,14,14,14]
    const float* __restrict__ theta,  // [NF,1,6,3]
    float* __restrict__ feats,        // [B][NF][PP][NQ]
    float* __restrict__ ip2)          // [PP]
{
    const int t = threadIdx.x;
    const int w = t >> 6;                       // wave -> which p
    const int p = blockIdx.x * PBLK + w;
    const int lane = t & 63;
    const int b = lane >> 2, f = lane & 3;

    __shared__ __align__(16) float scrot[NF*NQ][8];
    if (t < NF*NQ) {
        const float* a = theta + t*3;
        float s, c, sap, cap, sam, cam;
        __sincosf(0.5f*a[1], &s, &c);
        __sincosf(0.5f*(a[0]+a[2]), &sap, &cap);
        __sincosf(0.5f*(a[0]-a[2]), &sam, &cam);
        scrot[t][0] =  cap*c; scrot[t][1] = -sap*c;
        scrot[t][2] = -cam*s; scrot[t][3] = -sam*s;
        scrot[t][4] =  cam*s; scrot[t][5] = -sam*s;
        scrot[t][6] =  cap*c; scrot[t][7] =  sap*c;
    }
    __syncthreads();

    const int px = p/(NSIDE*NSIDE), py = (p/NSIDE)%NSIDE, pz = p%NSIDE;
    const float* xp = x + (size_t)b*GG3 + px*GG2 + py*GG + pz;
    #define SPV(i) xp[((i)/9)*GG2 + (((i)/3)%3)*GG + ((i)%3)]

    float ar[DD], ai[DD];
    ar[0] = 1.f; ai[0] = 0.f;

    // ---- encoding: gates on distinct qubits commute. Per qubit q the total
    // unitary's FIRST COLUMN (input is |0>) drives a sparse "spread" ladder.
    // qubit q<3: composed U_{q+6} @ U_q ; qubit q>=3: single U_q.
    #define ENC2(Q, MASK) { \
        float a0r,a0i,a1r,a1i; \
        rotcol(SPV(3*(Q)), SPV(3*(Q)+1), SPV(3*(Q)+2), a0r,a0i,a1r,a1i); \
        const int K2 = 3*((Q)+6); \
        float s_,c_,sap_,cap_,sam_,cam_; \
        __sincosf(0.5f*SPV(K2+1), &s_, &c_); \
        __sincosf(0.5f*(SPV(K2)+SPV(K2+2)), &sap_, &cap_); \
        __sincosf(0.5f*(SPV(K2)-SPV(K2+2)), &sam_, &cam_); \
        float b00r=cap_*c_, b00i=-sap_*c_, b01r=-cam_*s_, b01i=-sam_*s_; \
        float b10r=cam_*s_, b10i=-sam_*s_, b11r=cap_*c_,  b11i= sap_*c_; \
        float c0r = b00r*a0r - b00i*a0i + b01r*a1r - b01i*a1i; \
        float c0i = b00r*a0i + b00i*a0r + b01r*a1i + b01i*a1r; \
        float c1r = b10r*a0r - b10i*a0i + b11r*a1r - b11i*a1i; \
        float c1i = b10r*a0i + b10i*a0r + b11r*a1i + b11i*a1r; \
        spread<MASK>(ar, ai, c0r, c0i, c1r, c1i); }

    #define ENC1(Q, MASK) { \
        float c0r,c0i,c1r,c1i; \
        rotcol(SPV(3*(Q)), SPV(3*(Q)+1), SPV(3*(Q)+2), c0r,c0i,c1r,c1i); \
        spread<MASK>(ar, ai, c0r, c0i, c1r, c1i); }

    ENC2(0, 32) ENC2(1, 16) ENC2(2, 8)
    ENC1(3, 4)  ENC1(4, 2)  ENC1(5, 1)
    #undef ENC2
    #undef ENC1
    #undef SPV

    // ---- CRot layer for feature f: control i -> target (i+1)%6
    #define CR(I, CM, TM) { \
        float4 A  = *(const float4*)&scrot[f*NQ + (I)][0]; \
        float4 Bq = *(const float4*)&scrot[f*NQ + (I)][4]; \
        crot<CM, TM>(ar, ai, A.x, A.y, A.z, A.w, Bq.x, Bq.y, Bq.z, Bq.w); }

    CR(0, 32, 16) CR(1, 16, 8) CR(2, 8, 4) CR(3, 4, 2) CR(4, 2, 1) CR(5, 1, 32)
    #undef CR

    // ---- probabilities overwrite ar (ai dead after this)
    #pragma unroll
    for (int d = 0; d < DD; ++d) ar[d] = ar[d]*ar[d] + ai[d]*ai[d];

    // ---- loss pair-dots via DPP quad_perm (quad = same (p,b), f=0..3)
    float dot1 = 0.f, dot2 = 0.f, dot3 = 0.f;
    #pragma unroll
    for (int d = 0; d < DD; ++d) {
        dot1 += ar[d] * fdpp<0xB1>(ar[d]);
        dot2 += ar[d] * fdpp<0x4E>(ar[d]);
        dot3 += ar[d] * fdpp<0x1B>(ar[d]);
    }
    float lc = dot1*dot1 + dot2*dot2 + dot3*dot3;
    #pragma unroll
    for (int m = 1; m < 64; m <<= 1) lc += __shfl_xor(lc, m);
    if (lane == 0) ip2[p] = lc;

    // ---- expvals: signed in-place reduction tree over probs (in ar)
    float ev[NQ];
    #pragma unroll
    for (int lvl = 0; lvl < NQ; ++lvl) {
        const int n = DD >> (lvl + 1);
        float diff = 0.f;
        #pragma unroll
        for (int i = 0; i < n; ++i) diff += ar[2*i] - ar[2*i+1];
        ev[5 - lvl] = diff;
        #pragma unroll
        for (int i = 0; i < n; ++i) ar[i] = ar[2*i] + ar[2*i+1];
    }

    float* fo = feats + (((size_t)b*NF + f)*PP + p)*NQ;
    #pragma unroll
    for (int q = 0; q < NQ; ++q) fo[q] = ev[q];
}

// ---------- logits phase A: K-split, W read once ----------

__global__ __launch_bounds__(128) void logitsA(
    const float* __restrict__ feats,   // [BB][FEAT_LEN]
    const float* __restrict__ W,       // [NC][FEAT_LEN]
    float* __restrict__ partial)       // [NC][BB][NCHUNK]
{
    const int chunk = blockIdx.x;      // 0..80
    const int ctile = blockIdx.y;      // 0..4
    const int t = threadIdx.x;         // 128
    const int jbase = chunk * KCH;

    __shared__ __align__(16) float fs[BB][KCH + 4];

    #pragma unroll
    for (int i = 0; i < 16; ++i) {
        const int gi = i*128 + t;
        const int br = gi >> 7;
        const int c4 = gi & 127;
        float4 v = *(const float4*)(feats + (size_t)br*FEAT_LEN + jbase + c4*4);
        *(float4*)&fs[br][c4*4] = v;
    }
    __syncthreads();

    const int cl = t >> 4, b = t & 15;
    const int c = ctile*8 + cl;
    const float* wr = W + (size_t)c*FEAT_LEN + jbase;
    float acc = 0.f;
    #pragma unroll 8
    for (int j4 = 0; j4 < KCH/4; ++j4) {
        float4 wv = *(const float4*)(wr + j4*4);
        float4 fv = *(const float4*)&fs[b][j4*4];
        acc += wv.x*fv.x + wv.y*fv.y + wv.z*fv.z + wv.w*fv.w;
    }
    partial[((size_t)c*BB + b)*NCHUNK + chunk] = acc;
}

// ---------- phase B: logits reduce + bias, and loss reduce ----------

__global__ __launch_bounds__(768) void finalize_kernel(
    const float* __restrict__ partial, const float* __restrict__ bias,
    const float* __restrict__ ip2, float* __restrict__ out)
{
    const int t = threadIdx.x;
    if (t < BB*NC) {
        const int b = t / NC, c = t % NC;
        const float* pp = partial + ((size_t)c*BB + b)*NCHUNK;
        float acc = bias[c];
        #pragma unroll 27
        for (int i = 0; i < NCHUNK; ++i) acc += pp[i];
        out[t] = acc;
    } else if (t >= 704) {
        const int lane = t - 704;
        float acc = 0.f;
        for (int i = lane; i < PP; i += 64) acc += ip2[i];
        #pragma unroll
        for (int m = 1; m < 64; m <<= 1) acc += __shfl_xor(acc, m);
        if (lane == 0)
            out[BB*NC] = acc * (LAM / (float)(NF*(NF-1)) / (float)BB);
    }
}

extern "C" void kernel_launch(void* const* d_in, const int* in_sizes, int n_in,
                              void* d_out, int out_size, void* d_ws, size_t ws_size,
                              hipStream_t stream) {
    const float* x     = (const float*)d_in[0];  // [16,14,14,14]
    const float* theta = (const float*)d_in[1];  // [4,1,6,3]
    const float* W     = (const float*)d_in[2];  // [40,41472]
    const float* bias  = (const float*)d_in[3];  // [40]
    float* out = (float*)d_out;                  // [640 logits][1 loss]

    float* feats   = (float*)d_ws;                       // BB*FEAT_LEN
    float* ip2     = feats + (size_t)BB * FEAT_LEN;      // PP
    float* partial = ip2 + PP;                           // NC*BB*NCHUNK

    sim_kernel<<<PP/PBLK, 256, 0, stream>>>(x, theta, feats, ip2);
    logitsA<<<dim3(NCHUNK, CTILES), 128, 0, stream>>>(feats, W, partial);
    finalize_kernel<<<1, 768, 0, stream>>>(partial, bias, ip2, out);
}